// Round 4
// baseline (110.631 us; speedup 1.0000x reference)
//
#include <hip/hip_runtime.h>
#include <hip/hip_bf16.h>
#include <math.h>

// R13: GEMM 2-phase software pipeline. vs R12 (109.38us):
//  - gemm_qkv / gemm_out: double-buffered LDS; issue next K-tile's DMA BEFORE
//    computing current tile; ONE barrier per iter (was 2). The vmcnt(0) drain
//    at the barrier now pays max(0, DMA_lat - compute) instead of full
//    latency (old order: stage -> drain -> compute = zero overlap).
//    qkv LDS 56KB (2 blk/CU kept), out LDS 32KB.
//  - attn / cvt3 unchanged (R11/R12-proven).
// Measurement model: ~93us fixed harness overhead (2x 256MiB re-poison fills
// in the timed window; R10 evidence: 212us kernel -> 305.6us dur). Kernel
// budget ~16us; this targets the ~8us GEMM share.
// B=2, S=2048, IN=512, E=512, H=8, D=64, window=256 -> 257-key window.

typedef __bf16 bf16x8 __attribute__((ext_vector_type(8)));
typedef float f32x4 __attribute__((ext_vector_type(4)));

__device__ __forceinline__ unsigned short f2bf(float f) {
  unsigned u = __float_as_uint(f);
  unsigned r = u + 0x7FFFu + ((u >> 16) & 1u);  // RNE; finite inputs
  return (unsigned short)(r >> 16);
}

// async global->LDS DMA, 16B per lane; lds dest = wave-uniform base + lane*16
__device__ __forceinline__ void ldsdma16(void* lds, const void* g) {
  __builtin_amdgcn_global_load_lds(
      (const __attribute__((address_space(1))) unsigned int*)g,
      (__attribute__((address_space(3))) unsigned int*)lds, 16, 0, 0);
}

// ---------------- f32 -> bf16 conversion (x, qkv_w, o_w) ----------------
__global__ __launch_bounds__(256) void cvt3_kernel(
    const float* __restrict__ s0, unsigned short* __restrict__ d0, int n0,
    const float* __restrict__ s1, unsigned short* __restrict__ d1, int n1,
    const float* __restrict__ s2, unsigned short* __restrict__ d2, int n2) {
  int i4 = blockIdx.x * 256 + threadIdx.x;
  const int c0 = n0 >> 2, c1 = (n0 + n1) >> 2, c2 = (n0 + n1 + n2) >> 2;
  const float* s; unsigned short* d; int base4;
  if (i4 < c0)      { s = s0; d = d0; base4 = i4; }
  else if (i4 < c1) { s = s1; d = d1; base4 = i4 - c0; }
  else if (i4 < c2) { s = s2; d = d2; base4 = i4 - c1; }
  else return;
  float4 v = ((const float4*)s)[base4];
  ushort4 o;
  o.x = f2bf(v.x); o.y = f2bf(v.y); o.z = f2bf(v.z); o.w = f2bf(v.w);
  ((ushort4*)d)[base4] = o;
}

// ---------------- QKV projection GEMM (128x96, BK=64, dbuf pipeline) --------
// A(4096,512) @ Bw(1536,512)^T + bias -> qp (q*0.125*log2e), kp, vt (VT3).
// Grid 32x16 = 512 blocks -> 2 blocks/CU. LDS rows 128B, 16B chunks permuted
// chunk ^= (row&7) via pre-swizzled global src; same XOR on fragment reads.
__global__ __launch_bounds__(256) void gemm_qkv(
    const __hip_bfloat16* __restrict__ A, const __hip_bfloat16* __restrict__ Bw,
    const float* __restrict__ bias,
    __hip_bfloat16* __restrict__ qp, __hip_bfloat16* __restrict__ kpb,
    unsigned short* __restrict__ vtb) {
  __shared__ __hip_bfloat16 As[2][128 * 64];  // 2x16KB double buffer
  __shared__ __hip_bfloat16 Bs[2][96 * 64];   // 2x12KB

  const int tid = threadIdx.x, wave = tid >> 6, lane = tid & 63;
  const int m0 = blockIdx.x * 128, n0 = blockIdx.y * 96;
  const int wm = (wave >> 1) * 64, wn = (wave & 1) * 48;
  const int cl = lane & 15, ko = (lane >> 4) * 8;
  const int srow8 = lane >> 3;                // row within 8-row chunk
  const int scol = 8 * ((lane & 7) ^ srow8);  // elems, pre-swizzled source

  f32x4 acc[4][3] = {};

#define QKV_STAGE(buf, kk)                                                     \
  {                                                                            \
    _Pragma("unroll") for (int c = 0; c < 4; c++) {                            \
      const int R = wave * 8 + c * 32;                                         \
      ldsdma16(&As[buf][R * 64],                                               \
               A + (size_t)(m0 + R + srow8) * 512 + (kk) + scol);              \
    }                                                                          \
    _Pragma("unroll") for (int c = 0; c < 3; c++) {                            \
      const int R = wave * 8 + c * 32;                                         \
      ldsdma16(&Bs[buf][R * 64],                                               \
               Bw + (size_t)(n0 + R + srow8) * 512 + (kk) + scol);             \
    }                                                                          \
  }

  QKV_STAGE(0, 0);
  __syncthreads();  // drain prologue DMA -> buf0 ready
  int cur = 0;
  for (int t = 0; t < 8; t++) {
    if (t < 7) QKV_STAGE(cur ^ 1, (t + 1) * 64);  // overlap with compute below
#pragma unroll
    for (int ks = 0; ks < 2; ks++) {
      bf16x8 af[4], bf[3];
#pragma unroll
      for (int i = 0; i < 4; i++) {
        const int row = wm + cl + i * 16;
        af[i] = *(const bf16x8*)(
            &As[cur][row * 64 + ((ks * 32 + ko) ^ ((row & 7) << 3))]);
      }
#pragma unroll
      for (int i = 0; i < 3; i++) {
        const int row = wn + cl + i * 16;
        bf[i] = *(const bf16x8*)(
            &Bs[cur][row * 64 + ((ks * 32 + ko) ^ ((row & 7) << 3))]);
      }
#pragma unroll
      for (int mi = 0; mi < 4; mi++)
#pragma unroll
        for (int ni = 0; ni < 3; ni++)
          acc[mi][ni] = __builtin_amdgcn_mfma_f32_16x16x32_bf16(
              af[mi], bf[ni], acc[mi][ni], 0, 0, 0);
    }
    __syncthreads();  // reads of buf[cur] done + next DMA drained
    cur ^= 1;
  }
#undef QKV_STAGE

  const int crow = (lane >> 4) * 4;
#pragma unroll
  for (int mi = 0; mi < 4; mi++) {
    const int mb = m0 + wm + mi * 16 + crow;
    const int bq = mb >> 11, sl = mb & 2047;  // keys sl..sl+3, sl%4==0
#pragma unroll
    for (int ni = 0; ni < 3; ni++) {
      const int n = n0 + wn + ni * 16 + cl;
      const int h = n / 192;
      const int rem = n - h * 192;
      const int cat = rem >> 6;  // 0=q 1=k 2=v (uniform per 16-col group)
      const int d = rem & 63;
      const float bv = bias[n];
      const size_t bh = (size_t)bq * 8 + h;
      if (cat == 2) {
        ushort4 o;
        o.x = f2bf(acc[mi][ni][0] + bv);
        o.y = f2bf(acc[mi][ni][1] + bv);
        o.z = f2bf(acc[mi][ni][2] + bv);
        o.w = f2bf(acc[mi][ni][3] + bv);
        // VT3[bh][key/8][d][key%8]; keys sl..sl+3 share kb8 (sl%8 in {0,4})
        *(ushort4*)(vtb + bh * 131072 + (sl >> 3) * 512 + d * 8 + (sl & 7)) = o;
      } else {
        __hip_bfloat16* dst = (cat == 0) ? qp : kpb;
        // q: 1/sqrt(64) * log2(e) -> scores directly in exp2 domain
        const float sc = (cat == 0) ? 0.18033688011112042f : 1.0f;
#pragma unroll
        for (int r = 0; r < 4; r++)
          dst[(bh * 2048 + sl + r) * 64 + d] =
              __float2bfloat16((acc[mi][ni][r] + bv) * sc);
      }
    }
  }
}

// ---------------- MFMA sliding-window attention (R11/R12-proven) ------------
// block = (b,h, 64-query tile). Keys span [s0-128, s0+191] = 320 slots.
// Wave w owns q-rows [w*16, w*16+16): key tiles w..w+16. K staged to LDS
// (stride 72). Constant-max softmax (scores bounded in exp2 domain). P strips
// (per-wave 16x328, conflict-free) alias the dead K region. PV from VT3.
__global__ __launch_bounds__(256) void attn_mfma(
    const __hip_bfloat16* __restrict__ qp, const __hip_bfloat16* __restrict__ kp,
    const __hip_bfloat16* __restrict__ vt, const int* __restrict__ pm,
    __hip_bfloat16* __restrict__ vals) {
  __shared__ __hip_bfloat16 sKP[320 * 72];  // K tile (46KB); P strips alias
  __shared__ float sCM[320];                // pm/range addend: 0 or -3e38

  const int tid = threadIdx.x, wave = tid >> 6, lane = tid & 63;
  const int bid = blockIdx.x;
  const int s0 = (bid & 31) * 64;
  const int bh = bid >> 5;
  const int b = bh >> 3, h = bh & 7;
  const int t0 = s0 - 128;
  const int cl = lane & 15;
  const int g4 = (lane >> 4) * 4;   // C-layout row base
  const int ko = (lane >> 4) * 8;   // A/B-frag k offset

  // Q A-frags from global (16B/lane, L2-hot), hoisted above staging
  const __hip_bfloat16* qrow =
      qp + ((size_t)bh * 2048 + s0 + wave * 16 + cl) * 64 + ko;
  bf16x8 aq0 = *(const bf16x8*)(qrow);
  bf16x8 aq1 = *(const bf16x8*)(qrow + 32);

  // stage K tile: 320 rows x 128B, 8 threads/row x 16B, coalesced
  {
    const int e = (tid & 7) * 8;
#pragma unroll
    for (int i = 0; i < 10; i++) {
      int row = (tid >> 3) + i * 32;
      int t = t0 + row; t = min(max(t, 0), 2047);
      *(uint4*)(&sKP[row * 72 + e]) =
          *(const uint4*)(kp + ((size_t)bh * 2048 + t) * 64 + e);
    }
  }
  for (int c = tid; c < 320; c += 256) {
    int t = t0 + c;
    bool ok = (t >= 0 && t < 2048) && (pm[b * 2048 + t] != 0);
    sCM[c] = ok ? 0.0f : -3.0e38f;
  }
  __syncthreads();

  // QK^T: 17 key tiles x 2 k-steps; B-frags from LDS
  f32x4 acc[17];
#pragma unroll
  for (int i = 0; i < 17; i++) {
    const int krow = (wave + i) * 16 + cl;
    bf16x8 b0 = *(const bf16x8*)(&sKP[krow * 72 + ko]);
    bf16x8 b1 = *(const bf16x8*)(&sKP[krow * 72 + ko + 32]);
    f32x4 z = {};
    z = __builtin_amdgcn_mfma_f32_16x16x32_bf16(aq0, b0, z, 0, 0, 0);
    acc[i] = __builtin_amdgcn_mfma_f32_16x16x32_bf16(aq1, b1, z, 0, 0, 0);
  }

  // mask + exp2 + row-sum in ONE pass (constant-max; masked -> exact 0)
  float lsum[4] = {0.f, 0.f, 0.f, 0.f};
#pragma unroll
  for (int i = 0; i < 17; i++) {
    const float ca = sCM[(wave + i) * 16 + cl];
#pragma unroll
    for (int r = 0; r < 4; r++) {
      float sv = acc[i][r] + ca;
      if (i == 0) {                      // dlt = cl - (g4+r) may be < 0
        if (cl < g4 + r) sv = -3.0e38f;
      } else if (i == 16) {              // dlt = 256 + cl - (g4+r) may be > 256
        if (cl > g4 + r) sv = -3.0e38f;
      }
      float p = exp2f(sv);
      acc[i][r] = p;
      lsum[r] += p;
    }
  }
#pragma unroll
  for (int r = 0; r < 4; r++)
#pragma unroll
    for (int off = 1; off < 16; off <<= 1)
      lsum[r] += __shfl_xor(lsum[r], off);

  __syncthreads();  // all waves done reading K -> safe to alias P over it

  // write P (bf16) into per-wave 16x328 strip (absolute col indexing)
  __hip_bfloat16* sp = sKP + wave * 5248;
#pragma unroll
  for (int i = 0; i < 17; i++) {
    const int c = (wave + i) * 16 + cl;
#pragma unroll
    for (int r = 0; r < 4; r++)
      sp[(g4 + r) * 328 + c] = __float2bfloat16(acc[i][r]);
  }
  {  // zero the one extra tile the 32-aligned PV k-steps touch
    const int zt = (wave & 1) ? (wave - 1) : (wave + 17);
    const int zc = zt * 16 + cl;
#pragma unroll
    for (int r = 0; r < 4; r++)
      sp[(g4 + r) * 328 + zc] = __float2bfloat16(0.f);
  }
  // no further barrier: each wave reads only its own strip

  // PV: 9 k-steps of 32 keys; V B-frags from VT3, fully dense
  f32x4 oacc[4] = {};
  const int k0 = wave >> 1;  // k-step base: abs keys [k0*32, k0*32+288)
  const __hip_bfloat16* vbase = vt + (size_t)bh * 131072;
#pragma unroll
  for (int ks = 0; ks < 9; ks++) {
    const int kk = (k0 + ks) * 32 + ko;   // abs key col, %8==0
    bf16x8 pa = *(const bf16x8*)(&sp[cl * 328 + kk]);
    int tv = t0 + kk; tv = min(max(tv, 0), 2040);  // tv%8==0
    const __hip_bfloat16* vrow = vbase + (tv >> 3) * 512;
#pragma unroll
    for (int ni = 0; ni < 4; ni++) {
      const int d = ni * 16 + cl;
      bf16x8 vb = *(const bf16x8*)(vrow + d * 8);
      oacc[ni] = __builtin_amdgcn_mfma_f32_16x16x32_bf16(pa, vb, oacc[ni], 0, 0, 0);
    }
  }

  // epilogue: /l, pm-zero, store vals[s][h*64+d]
#pragma unroll
  for (int r = 0; r < 4; r++) {
    float linv = 1.0f / fmaxf(lsum[r], 1e-20f);
    const int qr = wave * 16 + g4 + r;
    if (sCM[qr + 128] != 0.0f) linv = 0.0f;  // fully-masked query -> 0
    const size_t obase = ((size_t)(b * 2048 + s0 + qr)) * 512 + h * 64 + cl;
#pragma unroll
    for (int ni = 0; ni < 4; ni++)
      vals[obase + ni * 16] = __float2bfloat16(oacc[ni][r] * linv);
  }
}

// ---------------- output projection GEMM (64x64, BK=64, dbuf pipeline) ------
// Grid 64x8 = 512 blocks -> 2 blocks/CU.
__global__ __launch_bounds__(256) void gemm_out(
    const __hip_bfloat16* __restrict__ A, const __hip_bfloat16* __restrict__ Bw,
    const float* __restrict__ bias, float* __restrict__ C) {
  __shared__ __hip_bfloat16 As[2][64 * 64];  // 2x8KB double buffer
  __shared__ __hip_bfloat16 Bs[2][64 * 64];

  const int tid = threadIdx.x, wave = tid >> 6, lane = tid & 63;
  const int m0 = blockIdx.x * 64, n0 = blockIdx.y * 64;
  const int wm = (wave >> 1) * 32, wn = (wave & 1) * 32;
  const int cl = lane & 15, ko = (lane >> 4) * 8;
  const int srow8 = lane >> 3;
  const int scol = 8 * ((lane & 7) ^ srow8);  // pre-swizzled source chunk

  f32x4 acc[2][2] = {};

#define OUT_STAGE(buf, kk)                                                     \
  {                                                                            \
    _Pragma("unroll") for (int c = 0; c < 2; c++) {                            \
      const int R = wave * 8 + c * 32;                                         \
      ldsdma16(&As[buf][R * 64],                                               \
               A + (size_t)(m0 + R + srow8) * 512 + (kk) + scol);              \
    }                                                                          \
    _Pragma("unroll") for (int c = 0; c < 2; c++) {                            \
      const int R = wave * 8 + c * 32;                                         \
      ldsdma16(&Bs[buf][R * 64],                                               \
               Bw + (size_t)(n0 + R + srow8) * 512 + (kk) + scol);             \
    }                                                                          \
  }

  OUT_STAGE(0, 0);
  __syncthreads();
  int cur = 0;
  for (int t = 0; t < 8; t++) {
    if (t < 7) OUT_STAGE(cur ^ 1, (t + 1) * 64);
#pragma unroll
    for (int ks = 0; ks < 2; ks++) {
      bf16x8 af[2], bf[2];
#pragma unroll
      for (int i = 0; i < 2; i++) {
        const int row = wm + cl + i * 16;
        af[i] = *(const bf16x8*)(
            &As[cur][row * 64 + ((ks * 32 + ko) ^ ((row & 7) << 3))]);
      }
#pragma unroll
      for (int i = 0; i < 2; i++) {
        const int row = wn + cl + i * 16;
        bf[i] = *(const bf16x8*)(
            &Bs[cur][row * 64 + ((ks * 32 + ko) ^ ((row & 7) << 3))]);
      }
#pragma unroll
      for (int mi = 0; mi < 2; mi++)
#pragma unroll
        for (int ni = 0; ni < 2; ni++)
          acc[mi][ni] = __builtin_amdgcn_mfma_f32_16x16x32_bf16(
              af[mi], bf[ni], acc[mi][ni], 0, 0, 0);
    }
    __syncthreads();
    cur ^= 1;
  }
#undef OUT_STAGE

  const int crow = (lane >> 4) * 4;
#pragma unroll
  for (int mi = 0; mi < 2; mi++) {
#pragma unroll
    for (int ni = 0; ni < 2; ni++) {
      const int n = n0 + wn + ni * 16 + cl;
      const float bv = bias[n];
      const int mb = m0 + wm + mi * 16 + crow;
#pragma unroll
      for (int r = 0; r < 4; r++)
        C[(size_t)(mb + r) * 512 + n] = acc[mi][ni][r] + bv;
    }
  }
}

extern "C" void kernel_launch(void* const* d_in, const int* in_sizes, int n_in,
                              void* d_out, int out_size, void* d_ws, size_t ws_size,
                              hipStream_t stream) {
  const float* x     = (const float*)d_in[0];   // (2,2048,512)
  const int*   pm    = (const int*)d_in[1];     // (2,2048)
  const float* qkv_w = (const float*)d_in[2];   // (1536,512)
  const float* qkv_b = (const float*)d_in[3];   // (1536,)
  const float* o_w   = (const float*)d_in[4];   // (512,512)
  const float* o_b   = (const float*)d_in[5];   // (512,)
  float* out = (float*)d_out;                   // (2,2048,512)

  __hip_bfloat16* wsb   = (__hip_bfloat16*)d_ws;
  __hip_bfloat16* xb    = wsb;               // 2097152
  __hip_bfloat16* wqkvb = wsb + 2097152;     // 786432
  __hip_bfloat16* wob   = wsb + 2883584;     // 262144
  __hip_bfloat16* qp    = wsb + 3145728;     // 2097152  [bh][s][64] (scaled)
  __hip_bfloat16* kp    = wsb + 5242880;     // 2097152  [bh][s][64]
  __hip_bfloat16* vt    = wsb + 7340032;     // 2097152  VT3[bh][k/8][d][k%8]
  __hip_bfloat16* vals  = wsb + 9437184;     // 2097152  [s][512]

  dim3 blk(256);
  cvt3_kernel<<<dim3(3072), blk, 0, stream>>>(
      x, (unsigned short*)xb, 2097152,
      qkv_w, (unsigned short*)wqkvb, 786432,
      o_w, (unsigned short*)wob, 262144);
  gemm_qkv<<<dim3(32, 16), blk, 0, stream>>>(
      xb, wqkvb, qkv_b, qp, kp, (unsigned short*)vt);
  attn_mfma<<<dim3(512), blk, 0, stream>>>(qp, kp, vt, pm, vals);
  gemm_out<<<dim3(64, 8), blk, 0, stream>>>(vals, wob, o_b, out);
}

// Round 5
// 108.253 us; speedup vs baseline: 1.0220x; 1.0220x over previous
//
#include <hip/hip_runtime.h>
#include <hip/hip_bf16.h>
#include <math.h>

// R14: revert GEMMs to R12 single-buffer (R13 dbuf +1.25us, m99/m100 effect);
// attn restructure:
//  - swapped QK^T: acc = mfma(K, Q) -> C col = q-row(cl), row = key(g4+r).
//    Keys become lane-local: P-writes 72x ds_write_b16 -> 18x ds_write_b64;
//    row-sum = lane-local + shfl_xor(16,32) (was 16 shuffles); mask addend
//    read as float4 (17 loads, was 68).
//  - K staged via global_load_lds (stride 64, XOR chunk swizzle both-sides,
//    pre-swizzled source) -- drops 10 uint4 + 10 ds_write_b128 per thread.
//  - P strip layout unchanged (sp[cl*328+key]) -> PV identical.
// Measurement model: ~93us fixed harness fills in timed window (R10 evidence);
// addressable kernel budget ~16us.
// B=2, S=2048, IN=512, E=512, H=8, D=64, window=256 -> 257-key window.

typedef __bf16 bf16x8 __attribute__((ext_vector_type(8)));
typedef float f32x4 __attribute__((ext_vector_type(4)));

__device__ __forceinline__ unsigned short f2bf(float f) {
  unsigned u = __float_as_uint(f);
  unsigned r = u + 0x7FFFu + ((u >> 16) & 1u);  // RNE; finite inputs
  return (unsigned short)(r >> 16);
}

// async global->LDS DMA, 16B per lane; lds dest = wave-uniform base + lane*16
__device__ __forceinline__ void ldsdma16(void* lds, const void* g) {
  __builtin_amdgcn_global_load_lds(
      (const __attribute__((address_space(1))) unsigned int*)g,
      (__attribute__((address_space(3))) unsigned int*)lds, 16, 0, 0);
}

// ---------------- f32 -> bf16 conversion (x, qkv_w, o_w) ----------------
__global__ __launch_bounds__(256) void cvt3_kernel(
    const float* __restrict__ s0, unsigned short* __restrict__ d0, int n0,
    const float* __restrict__ s1, unsigned short* __restrict__ d1, int n1,
    const float* __restrict__ s2, unsigned short* __restrict__ d2, int n2) {
  int i4 = blockIdx.x * 256 + threadIdx.x;
  const int c0 = n0 >> 2, c1 = (n0 + n1) >> 2, c2 = (n0 + n1 + n2) >> 2;
  const float* s; unsigned short* d; int base4;
  if (i4 < c0)      { s = s0; d = d0; base4 = i4; }
  else if (i4 < c1) { s = s1; d = d1; base4 = i4 - c0; }
  else if (i4 < c2) { s = s2; d = d2; base4 = i4 - c1; }
  else return;
  float4 v = ((const float4*)s)[base4];
  ushort4 o;
  o.x = f2bf(v.x); o.y = f2bf(v.y); o.z = f2bf(v.z); o.w = f2bf(v.w);
  ((ushort4*)d)[base4] = o;
}

// ---------------- QKV projection GEMM (128x96 tile, BK=64, swizzled) --------
// R12-proven form. A(4096,512) @ Bw(1536,512)^T + bias -> qp, kp, vt (VT3).
// Grid 32x16 = 512 blocks -> 2 blocks/CU. LDS rows 128B, 16B chunks permuted
// chunk ^= (row&7) via pre-swizzled global src; same XOR on fragment reads.
__global__ __launch_bounds__(256) void gemm_qkv(
    const __hip_bfloat16* __restrict__ A, const __hip_bfloat16* __restrict__ Bw,
    const float* __restrict__ bias,
    __hip_bfloat16* __restrict__ qp, __hip_bfloat16* __restrict__ kpb,
    unsigned short* __restrict__ vtb) {
  __shared__ __hip_bfloat16 As[128 * 64];  // 16KB, 128B rows, swizzled chunks
  __shared__ __hip_bfloat16 Bs[96 * 64];   // 12KB

  const int tid = threadIdx.x, wave = tid >> 6, lane = tid & 63;
  const int m0 = blockIdx.x * 128, n0 = blockIdx.y * 96;
  const int wm = (wave >> 1) * 64, wn = (wave & 1) * 48;
  const int cl = lane & 15, ko = (lane >> 4) * 8;
  const int srow8 = lane >> 3;                       // row within 8-row chunk
  const int scol = 8 * ((lane & 7) ^ srow8);         // elems, pre-swizzled

  f32x4 acc[4][3] = {};

  for (int k0 = 0; k0 < 512; k0 += 64) {
    __syncthreads();  // prev iter frag reads done
#pragma unroll
    for (int c = 0; c < 4; c++) {  // A: 128 rows = 16 chunks, 4/wave
      const int R = wave * 8 + c * 32;
      ldsdma16(&As[R * 64], A + (size_t)(m0 + R + srow8) * 512 + k0 + scol);
    }
#pragma unroll
    for (int c = 0; c < 3; c++) {  // B: 96 rows = 12 chunks, 3/wave
      const int R = wave * 8 + c * 32;
      ldsdma16(&Bs[R * 64], Bw + (size_t)(n0 + R + srow8) * 512 + k0 + scol);
    }
    __syncthreads();  // vmcnt(0) drain + barrier -> LDS ready

#pragma unroll
    for (int ks = 0; ks < 2; ks++) {
      bf16x8 af[4], bf[3];
#pragma unroll
      for (int i = 0; i < 4; i++) {
        const int row = wm + cl + i * 16;
        af[i] = *(const bf16x8*)(&As[row * 64 + ((ks * 32 + ko) ^ ((row & 7) << 3))]);
      }
#pragma unroll
      for (int i = 0; i < 3; i++) {
        const int row = wn + cl + i * 16;
        bf[i] = *(const bf16x8*)(&Bs[row * 64 + ((ks * 32 + ko) ^ ((row & 7) << 3))]);
      }
#pragma unroll
      for (int mi = 0; mi < 4; mi++)
#pragma unroll
        for (int ni = 0; ni < 3; ni++)
          acc[mi][ni] = __builtin_amdgcn_mfma_f32_16x16x32_bf16(
              af[mi], bf[ni], acc[mi][ni], 0, 0, 0);
    }
  }

  const int crow = (lane >> 4) * 4;
#pragma unroll
  for (int mi = 0; mi < 4; mi++) {
    const int mb = m0 + wm + mi * 16 + crow;
    const int bq = mb >> 11, sl = mb & 2047;  // keys sl..sl+3, sl%4==0
#pragma unroll
    for (int ni = 0; ni < 3; ni++) {
      const int n = n0 + wn + ni * 16 + cl;
      const int h = n / 192;
      const int rem = n - h * 192;
      const int cat = rem >> 6;  // 0=q 1=k 2=v (uniform per 16-col group)
      const int d = rem & 63;
      const float bv = bias[n];
      const size_t bh = (size_t)bq * 8 + h;
      if (cat == 2) {
        ushort4 o;
        o.x = f2bf(acc[mi][ni][0] + bv);
        o.y = f2bf(acc[mi][ni][1] + bv);
        o.z = f2bf(acc[mi][ni][2] + bv);
        o.w = f2bf(acc[mi][ni][3] + bv);
        // VT3[bh][key/8][d][key%8]; keys sl..sl+3 share kb8 (sl%8 in {0,4})
        *(ushort4*)(vtb + bh * 131072 + (sl >> 3) * 512 + d * 8 + (sl & 7)) = o;
      } else {
        __hip_bfloat16* dst = (cat == 0) ? qp : kpb;
        // q: 1/sqrt(64) * log2(e) -> scores directly in exp2 domain
        const float sc = (cat == 0) ? 0.18033688011112042f : 1.0f;
#pragma unroll
        for (int r = 0; r < 4; r++)
          dst[(bh * 2048 + sl + r) * 64 + d] =
              __float2bfloat16((acc[mi][ni][r] + bv) * sc);
      }
    }
  }
}

// ---------------- MFMA sliding-window attention (swapped QK^T) --------------
// block = (b,h, 64-query tile). Keys span [s0-128, s0+191] = 320 slots.
// Wave w owns q-rows [w*16, w*16+16): key tiles w..w+16. K staged via lds-dma
// (stride 64, XOR chunk swizzle). QK^T computed as mfma(K, Q): C col = q-row
// (cl), row = key (g4+r) -> keys lane-local. Constant-max softmax. P written
// as packed b64 into per-wave 16x328 strips aliasing the K region. PV from
// VT3 (dense 16B/lane). 2 barriers.
__global__ __launch_bounds__(256) void attn_mfma(
    const __hip_bfloat16* __restrict__ qp, const __hip_bfloat16* __restrict__ kp,
    const __hip_bfloat16* __restrict__ vt, const int* __restrict__ pm,
    __hip_bfloat16* __restrict__ vals) {
  __shared__ __hip_bfloat16 sKP[320 * 72];  // K in first 40KB; P strips alias
  __shared__ float sCM[320];                // pm/range addend: 0 or -3e38

  const int tid = threadIdx.x, wave = tid >> 6, lane = tid & 63;
  const int bid = blockIdx.x;
  const int s0 = (bid & 31) * 64;
  const int bh = bid >> 5;
  const int b = bh >> 3, h = bh & 7;
  const int t0 = s0 - 128;
  const int cl = lane & 15;
  const int g4 = (lane >> 4) * 4;   // C-layout row base (now: key sub-offset)
  const int ko = (lane >> 4) * 8;   // A/B-frag k offset (d-dim chunk)

  // Q B-frags from global (16B/lane, L2-hot), hoisted above staging
  const __hip_bfloat16* qrow =
      qp + ((size_t)bh * 2048 + s0 + wave * 16 + cl) * 64 + ko;
  bf16x8 aq0 = *(const bf16x8*)(qrow);
  bf16x8 aq1 = *(const bf16x8*)(qrow + 32);

  // stage K tile via lds-dma: 320 rows x 128B, stride 64 elems, chunk XOR
  // swizzle (LDS chunk c of row r holds global chunk c^(r&7)).
  {
    const int srow8 = lane >> 3;                 // row within 8-row group
    const int scol = 8 * ((lane & 7) ^ srow8);   // pre-swizzled source chunk
#pragma unroll
    for (int i = 0; i < 10; i++) {
      const int rbase = i * 32 + wave * 8;       // wave-uniform
      int t = t0 + rbase + srow8;
      t = min(max(t, 0), 2047);
      ldsdma16(&sKP[rbase * 64], kp + ((size_t)bh * 2048 + t) * 64 + scol);
    }
  }
  for (int c = tid; c < 320; c += 256) {
    int t = t0 + c;
    bool ok = (t >= 0 && t < 2048) && (pm[b * 2048 + t] != 0);
    sCM[c] = ok ? 0.0f : -3.0e38f;
  }
  __syncthreads();

  // QK^T swapped: 17 key tiles x 2 k-steps; A=K (rows=keys), B=Q (cols=q).
  f32x4 acc[17];
#pragma unroll
  for (int i = 0; i < 17; i++) {
    const int krow = (wave + i) * 16 + cl;       // krow&7 == cl&7
    const int kb = krow * 64;
    const int sw = (cl & 7) << 3;
    bf16x8 k0f = *(const bf16x8*)(&sKP[kb + (ko ^ sw)]);
    bf16x8 k1f = *(const bf16x8*)(&sKP[kb + ((ko + 32) ^ sw)]);
    f32x4 z = {};
    z = __builtin_amdgcn_mfma_f32_16x16x32_bf16(k0f, aq0, z, 0, 0, 0);
    acc[i] = __builtin_amdgcn_mfma_f32_16x16x32_bf16(k1f, aq1, z, 0, 0, 0);
  }

  // mask + exp2 + row-sum (row = q-row = cl; keys lane-local).
  // c - qi = 16i + (g4+r) - cl must be in [0,256]; interior always valid.
  float lsum = 0.f;
#pragma unroll
  for (int i = 0; i < 17; i++) {
    const f32x4 cm = *(const f32x4*)(&sCM[(wave + i) * 16 + g4]);
#pragma unroll
    for (int r = 0; r < 4; r++) {
      float sv = acc[i][r] + cm[r];
      if (i == 0) {                      // mask if key offset < q offset
        if (g4 + r < cl) sv = -3.0e38f;
      } else if (i == 16) {              // mask if key offset > q offset
        if (g4 + r > cl) sv = -3.0e38f;
      }
      float p = exp2f(sv);               // masked -> exact 0
      acc[i][r] = p;
      lsum += p;
    }
  }
  lsum += __shfl_xor(lsum, 16);
  lsum += __shfl_xor(lsum, 32);  // lanes {cl, cl+16, cl+32, cl+48} share sum

  __syncthreads();  // all waves done reading K -> safe to alias P over it

  // write P (bf16) packed b64: row cl, 4 consecutive keys per tile
  __hip_bfloat16* sp = sKP + wave * 5248;
#pragma unroll
  for (int i = 0; i < 17; i++) {
    ushort4 pk;
    pk.x = f2bf(acc[i][0]); pk.y = f2bf(acc[i][1]);
    pk.z = f2bf(acc[i][2]); pk.w = f2bf(acc[i][3]);
    *(ushort4*)(&sp[cl * 328 + (wave + i) * 16 + g4]) = pk;
  }
  {  // zero the one extra tile the 32-aligned PV k-steps touch
    const int zt = (wave & 1) ? (wave - 1) : (wave + 17);
    ushort4 zz = {0, 0, 0, 0};
    *(ushort4*)(&sp[cl * 328 + zt * 16 + g4]) = zz;
  }
  // no further barrier: each wave reads only its own strip

  // PV: 9 k-steps of 32 keys; V B-frags from VT3, fully dense
  f32x4 oacc[4] = {};
  const int k0 = wave >> 1;  // k-step base: abs keys [k0*32, k0*32+288)
  const __hip_bfloat16* vbase = vt + (size_t)bh * 131072;
#pragma unroll
  for (int ks = 0; ks < 9; ks++) {
    const int kk = (k0 + ks) * 32 + ko;   // abs key col, %8==0
    bf16x8 pa = *(const bf16x8*)(&sp[cl * 328 + kk]);
    int tv = t0 + kk; tv = min(max(tv, 0), 2040);  // tv%8==0
    const __hip_bfloat16* vrow = vbase + (tv >> 3) * 512;
#pragma unroll
    for (int ni = 0; ni < 4; ni++) {
      const int d = ni * 16 + cl;
      bf16x8 vb = *(const bf16x8*)(vrow + d * 8);
      oacc[ni] = __builtin_amdgcn_mfma_f32_16x16x32_bf16(pa, vb, oacc[ni], 0, 0, 0);
    }
  }

  // epilogue: /l (broadcast from lane g4+r), pm-zero, store vals[s][h*64+d]
#pragma unroll
  for (int r = 0; r < 4; r++) {
    const float ls = __shfl(lsum, g4 + r);  // lane g4+r holds row g4+r sum
    float linv = 1.0f / fmaxf(ls, 1e-20f);
    const int qr = wave * 16 + g4 + r;
    if (sCM[qr + 128] != 0.0f) linv = 0.0f;  // fully-masked query -> 0
    const size_t obase = ((size_t)(b * 2048 + s0 + qr)) * 512 + h * 64 + cl;
#pragma unroll
    for (int ni = 0; ni < 4; ni++)
      vals[obase + ni * 16] = __float2bfloat16(oacc[ni][r] * linv);
  }
}

// ---------------- output projection GEMM (64x64 tile, BK=64, swizzled) ------
// R12-proven form. Grid 64x8 = 512 blocks -> 2 blocks/CU.
__global__ __launch_bounds__(256) void gemm_out(
    const __hip_bfloat16* __restrict__ A, const __hip_bfloat16* __restrict__ Bw,
    const float* __restrict__ bias, float* __restrict__ C) {
  __shared__ __hip_bfloat16 As[64 * 64];  // 8KB, 128B rows, swizzled chunks
  __shared__ __hip_bfloat16 Bs[64 * 64];

  const int tid = threadIdx.x, wave = tid >> 6, lane = tid & 63;
  const int m0 = blockIdx.x * 64, n0 = blockIdx.y * 64;
  const int wm = (wave >> 1) * 32, wn = (wave & 1) * 32;
  const int cl = lane & 15, ko = (lane >> 4) * 8;
  const int srow8 = lane >> 3;
  const int scol = 8 * ((lane & 7) ^ srow8);  // pre-swizzled source chunk

  f32x4 acc[2][2] = {};

  for (int k0 = 0; k0 < 512; k0 += 64) {
    __syncthreads();
#pragma unroll
    for (int c = 0; c < 2; c++) {  // A: 64 rows = 8 chunks, 2/wave
      const int R = wave * 8 + c * 32;
      ldsdma16(&As[R * 64], A + (size_t)(m0 + R + srow8) * 512 + k0 + scol);
    }
#pragma unroll
    for (int c = 0; c < 2; c++) {  // B: 64 rows = 8 chunks, 2/wave
      const int R = wave * 8 + c * 32;
      ldsdma16(&Bs[R * 64], Bw + (size_t)(n0 + R + srow8) * 512 + k0 + scol);
    }
    __syncthreads();

#pragma unroll
    for (int ks = 0; ks < 2; ks++) {
      bf16x8 af[2], bf[2];
#pragma unroll
      for (int i = 0; i < 2; i++) {
        const int row = wm + cl + i * 16;
        af[i] = *(const bf16x8*)(&As[row * 64 + ((ks * 32 + ko) ^ ((row & 7) << 3))]);
      }
#pragma unroll
      for (int i = 0; i < 2; i++) {
        const int row = wn + cl + i * 16;
        bf[i] = *(const bf16x8*)(&Bs[row * 64 + ((ks * 32 + ko) ^ ((row & 7) << 3))]);
      }
#pragma unroll
      for (int mi = 0; mi < 2; mi++)
#pragma unroll
        for (int ni = 0; ni < 2; ni++)
          acc[mi][ni] = __builtin_amdgcn_mfma_f32_16x16x32_bf16(
              af[mi], bf[ni], acc[mi][ni], 0, 0, 0);
    }
  }

  const int crow = (lane >> 4) * 4;
#pragma unroll
  for (int mi = 0; mi < 2; mi++) {
#pragma unroll
    for (int ni = 0; ni < 2; ni++) {
      const int n = n0 + wn + ni * 16 + cl;
      const float bv = bias[n];
      const int mb = m0 + wm + mi * 16 + crow;
#pragma unroll
      for (int r = 0; r < 4; r++)
        C[(size_t)(mb + r) * 512 + n] = acc[mi][ni][r] + bv;
    }
  }
}

extern "C" void kernel_launch(void* const* d_in, const int* in_sizes, int n_in,
                              void* d_out, int out_size, void* d_ws, size_t ws_size,
                              hipStream_t stream) {
  const float* x     = (const float*)d_in[0];   // (2,2048,512)
  const int*   pm    = (const int*)d_in[1];     // (2,2048)
  const float* qkv_w = (const float*)d_in[2];   // (1536,512)
  const float* qkv_b = (const float*)d_in[3];   // (1536,)
  const float* o_w   = (const float*)d_in[4];   // (512,512)
  const float* o_b   = (const float*)d_in[5];   // (512,)
  float* out = (float*)d_out;                   // (2,2048,512)

  __hip_bfloat16* wsb   = (__hip_bfloat16*)d_ws;
  __hip_bfloat16* xb    = wsb;               // 2097152
  __hip_bfloat16* wqkvb = wsb + 2097152;     // 786432
  __hip_bfloat16* wob   = wsb + 2883584;     // 262144
  __hip_bfloat16* qp    = wsb + 3145728;     // 2097152  [bh][s][64] (scaled)
  __hip_bfloat16* kp    = wsb + 5242880;     // 2097152  [bh][s][64]
  __hip_bfloat16* vt    = wsb + 7340032;     // 2097152  VT3[bh][k/8][d][k%8]
  __hip_bfloat16* vals  = wsb + 9437184;     // 2097152  [s][512]

  dim3 blk(256);
  cvt3_kernel<<<dim3(3072), blk, 0, stream>>>(
      x, (unsigned short*)xb, 2097152,
      qkv_w, (unsigned short*)wqkvb, 786432,
      o_w, (unsigned short*)wob, 262144);
  gemm_qkv<<<dim3(32, 16), blk, 0, stream>>>(
      xb, wqkvb, qkv_b, qp, kp, (unsigned short*)vt);
  attn_mfma<<<dim3(512), blk, 0, stream>>>(qp, kp, vt, pm, vals);
  gemm_out<<<dim3(64, 8), blk, 0, stream>>>(vals, wob, o_b, out);
}

// Round 6
// 107.344 us; speedup vs baseline: 1.0306x; 1.0085x over previous
//
#include <hip/hip_runtime.h>
#include <hip/hip_bf16.h>
#include <math.h>

// R15: vs R14 (108.25us):
//  - gemm_qkv / gemm_out: BK 64->128 (halves barrier+vmcnt(0) drains 16->8,
//    the R12-proven lever). LDS 56KB / 32KB -- both keep 2 blocks/CU at
//    grid 512 (m132's occupancy cliff avoided). Same XOR chunk swizzle:
//    write side pre-swizzled global source chunk c^(row&7), read side
//    (ks*32+ko)^((row&7)<<3); 4-row-per-issue dma geometry.
//  - cvt3: 1024 blocks x 3 grid-strided float4 (less dispatch ramp).
//  - attn unchanged (R14-proven swapped-QK^T form).
// Measurement model: ~93us fixed harness fills in timed window; addressable
// kernel budget ~15us.
// B=2, S=2048, IN=512, E=512, H=8, D=64, window=256 -> 257-key window.

typedef __bf16 bf16x8 __attribute__((ext_vector_type(8)));
typedef float f32x4 __attribute__((ext_vector_type(4)));

__device__ __forceinline__ unsigned short f2bf(float f) {
  unsigned u = __float_as_uint(f);
  unsigned r = u + 0x7FFFu + ((u >> 16) & 1u);  // RNE; finite inputs
  return (unsigned short)(r >> 16);
}

// async global->LDS DMA, 16B per lane; lds dest = wave-uniform base + lane*16
__device__ __forceinline__ void ldsdma16(void* lds, const void* g) {
  __builtin_amdgcn_global_load_lds(
      (const __attribute__((address_space(1))) unsigned int*)g,
      (__attribute__((address_space(3))) unsigned int*)lds, 16, 0, 0);
}

// ---------------- f32 -> bf16 conversion (x, qkv_w, o_w) ----------------
// 1024 blocks x 256 threads x 3 float4 (grid-stride) = 786432 float4 exact.
__global__ __launch_bounds__(256) void cvt3_kernel(
    const float* __restrict__ s0, unsigned short* __restrict__ d0, int n0,
    const float* __restrict__ s1, unsigned short* __restrict__ d1, int n1,
    const float* __restrict__ s2, unsigned short* __restrict__ d2, int n2) {
  const int c0 = n0 >> 2, c1 = (n0 + n1) >> 2, c2 = (n0 + n1 + n2) >> 2;
  const int base = blockIdx.x * 256 + threadIdx.x;
#pragma unroll
  for (int it = 0; it < 3; it++) {
    const int i4 = base + it * 262144;
    const float* s; unsigned short* d; int base4;
    if (i4 < c0)      { s = s0; d = d0; base4 = i4; }
    else if (i4 < c1) { s = s1; d = d1; base4 = i4 - c0; }
    else if (i4 < c2) { s = s2; d = d2; base4 = i4 - c1; }
    else continue;
    float4 v = ((const float4*)s)[base4];
    ushort4 o;
    o.x = f2bf(v.x); o.y = f2bf(v.y); o.z = f2bf(v.z); o.w = f2bf(v.w);
    ((ushort4*)d)[base4] = o;
  }
}

// ---------------- QKV projection GEMM (128x96 tile, BK=128, swizzled) -------
// A(4096,512) @ Bw(1536,512)^T + bias -> qp (q*0.125*log2e), kp, vt (VT3).
// Grid 32x16 = 512 blocks -> 2 blocks/CU (LDS 56KB). Rows 256B = 16 chunks of
// 16B; LDS chunk c of row r holds global chunk c^(r&7) (pre-swizzled source);
// fragment reads XOR the same involution.
__global__ __launch_bounds__(256) void gemm_qkv(
    const __hip_bfloat16* __restrict__ A, const __hip_bfloat16* __restrict__ Bw,
    const float* __restrict__ bias,
    __hip_bfloat16* __restrict__ qp, __hip_bfloat16* __restrict__ kpb,
    unsigned short* __restrict__ vtb) {
  __shared__ __hip_bfloat16 As[128 * 128];  // 32KB
  __shared__ __hip_bfloat16 Bs[96 * 128];   // 24KB

  const int tid = threadIdx.x, wave = tid >> 6, lane = tid & 63;
  const int m0 = blockIdx.x * 128, n0 = blockIdx.y * 96;
  const int wm = (wave >> 1) * 64, wn = (wave & 1) * 48;
  const int cl = lane & 15, ko = (lane >> 4) * 8;
  // dma geometry: each issue = 1024B = 4 rows x 256B; 16 lanes/row.
  const int srow = lane >> 4;  // row within 4-row group

  f32x4 acc[4][3] = {};

  for (int k0 = 0; k0 < 512; k0 += 128) {
    __syncthreads();  // prev iter frag reads done
#pragma unroll
    for (int c = 0; c < 8; c++) {  // A: 128 rows = 32 groups of 4, 8/wave
      const int R = (wave + c * 4) * 4;  // multiple of 4
      const int scol = 8 * ((lane & 15) ^ ((R & 4) + srow));
      ldsdma16(&As[R * 128], A + (size_t)(m0 + R + srow) * 512 + k0 + scol);
    }
#pragma unroll
    for (int c = 0; c < 6; c++) {  // B: 96 rows = 24 groups of 4, 6/wave
      const int R = (wave + c * 4) * 4;
      const int scol = 8 * ((lane & 15) ^ ((R & 4) + srow));
      ldsdma16(&Bs[R * 128], Bw + (size_t)(n0 + R + srow) * 512 + k0 + scol);
    }
    __syncthreads();  // vmcnt(0) drain + barrier -> LDS ready

#pragma unroll
    for (int ks = 0; ks < 4; ks++) {
      bf16x8 af[4], bf[3];
#pragma unroll
      for (int i = 0; i < 4; i++) {
        const int row = wm + cl + i * 16;
        af[i] = *(const bf16x8*)(
            &As[row * 128 + ((ks * 32 + ko) ^ ((row & 7) << 3))]);
      }
#pragma unroll
      for (int i = 0; i < 3; i++) {
        const int row = wn + cl + i * 16;
        bf[i] = *(const bf16x8*)(
            &Bs[row * 128 + ((ks * 32 + ko) ^ ((row & 7) << 3))]);
      }
#pragma unroll
      for (int mi = 0; mi < 4; mi++)
#pragma unroll
        for (int ni = 0; ni < 3; ni++)
          acc[mi][ni] = __builtin_amdgcn_mfma_f32_16x16x32_bf16(
              af[mi], bf[ni], acc[mi][ni], 0, 0, 0);
    }
  }

  const int crow = (lane >> 4) * 4;
#pragma unroll
  for (int mi = 0; mi < 4; mi++) {
    const int mb = m0 + wm + mi * 16 + crow;
    const int bq = mb >> 11, sl = mb & 2047;  // keys sl..sl+3, sl%4==0
#pragma unroll
    for (int ni = 0; ni < 3; ni++) {
      const int n = n0 + wn + ni * 16 + cl;
      const int h = n / 192;
      const int rem = n - h * 192;
      const int cat = rem >> 6;  // 0=q 1=k 2=v (uniform per 16-col group)
      const int d = rem & 63;
      const float bv = bias[n];
      const size_t bh = (size_t)bq * 8 + h;
      if (cat == 2) {
        ushort4 o;
        o.x = f2bf(acc[mi][ni][0] + bv);
        o.y = f2bf(acc[mi][ni][1] + bv);
        o.z = f2bf(acc[mi][ni][2] + bv);
        o.w = f2bf(acc[mi][ni][3] + bv);
        // VT3[bh][key/8][d][key%8]; keys sl..sl+3 share kb8 (sl%8 in {0,4})
        *(ushort4*)(vtb + bh * 131072 + (sl >> 3) * 512 + d * 8 + (sl & 7)) = o;
      } else {
        __hip_bfloat16* dst = (cat == 0) ? qp : kpb;
        // q: 1/sqrt(64) * log2(e) -> scores directly in exp2 domain
        const float sc = (cat == 0) ? 0.18033688011112042f : 1.0f;
#pragma unroll
        for (int r = 0; r < 4; r++)
          dst[(bh * 2048 + sl + r) * 64 + d] =
              __float2bfloat16((acc[mi][ni][r] + bv) * sc);
      }
    }
  }
}

// ---------------- MFMA sliding-window attention (R14-proven) ----------------
// block = (b,h, 64-query tile). Keys span [s0-128, s0+191] = 320 slots.
// Wave w owns q-rows [w*16, w*16+16): key tiles w..w+16. K staged via lds-dma
// (stride 64, XOR chunk swizzle). QK^T computed as mfma(K, Q): C col = q-row
// (cl), row = key (g4+r) -> keys lane-local. Constant-max softmax. P written
// as packed b64 into per-wave 16x328 strips aliasing the K region. PV from
// VT3 (dense 16B/lane). 2 barriers.
__global__ __launch_bounds__(256) void attn_mfma(
    const __hip_bfloat16* __restrict__ qp, const __hip_bfloat16* __restrict__ kp,
    const __hip_bfloat16* __restrict__ vt, const int* __restrict__ pm,
    __hip_bfloat16* __restrict__ vals) {
  __shared__ __hip_bfloat16 sKP[320 * 72];  // K in first 40KB; P strips alias
  __shared__ float sCM[320];                // pm/range addend: 0 or -3e38

  const int tid = threadIdx.x, wave = tid >> 6, lane = tid & 63;
  const int bid = blockIdx.x;
  const int s0 = (bid & 31) * 64;
  const int bh = bid >> 5;
  const int b = bh >> 3, h = bh & 7;
  const int t0 = s0 - 128;
  const int cl = lane & 15;
  const int g4 = (lane >> 4) * 4;   // key sub-offset base
  const int ko = (lane >> 4) * 8;   // A/B-frag k offset (d-dim chunk)

  // Q B-frags from global (16B/lane, L2-hot), hoisted above staging
  const __hip_bfloat16* qrow =
      qp + ((size_t)bh * 2048 + s0 + wave * 16 + cl) * 64 + ko;
  bf16x8 aq0 = *(const bf16x8*)(qrow);
  bf16x8 aq1 = *(const bf16x8*)(qrow + 32);

  // stage K tile via lds-dma: 320 rows x 128B, stride 64 elems, chunk XOR
  // swizzle (LDS chunk c of row r holds global chunk c^(r&7)).
  {
    const int srow8 = lane >> 3;                 // row within 8-row group
    const int scol = 8 * ((lane & 7) ^ srow8);   // pre-swizzled source chunk
#pragma unroll
    for (int i = 0; i < 10; i++) {
      const int rbase = i * 32 + wave * 8;       // wave-uniform
      int t = t0 + rbase + srow8;
      t = min(max(t, 0), 2047);
      ldsdma16(&sKP[rbase * 64], kp + ((size_t)bh * 2048 + t) * 64 + scol);
    }
  }
  for (int c = tid; c < 320; c += 256) {
    int t = t0 + c;
    bool ok = (t >= 0 && t < 2048) && (pm[b * 2048 + t] != 0);
    sCM[c] = ok ? 0.0f : -3.0e38f;
  }
  __syncthreads();

  // QK^T swapped: 17 key tiles x 2 k-steps; A=K (rows=keys), B=Q (cols=q).
  f32x4 acc[17];
#pragma unroll
  for (int i = 0; i < 17; i++) {
    const int krow = (wave + i) * 16 + cl;       // krow&7 == cl&7
    const int kb = krow * 64;
    const int sw = (cl & 7) << 3;
    bf16x8 k0f = *(const bf16x8*)(&sKP[kb + (ko ^ sw)]);
    bf16x8 k1f = *(const bf16x8*)(&sKP[kb + ((ko + 32) ^ sw)]);
    f32x4 z = {};
    z = __builtin_amdgcn_mfma_f32_16x16x32_bf16(k0f, aq0, z, 0, 0, 0);
    acc[i] = __builtin_amdgcn_mfma_f32_16x16x32_bf16(k1f, aq1, z, 0, 0, 0);
  }

  // mask + exp2 + row-sum (row = q-row = cl; keys lane-local).
  float lsum = 0.f;
#pragma unroll
  for (int i = 0; i < 17; i++) {
    const f32x4 cm = *(const f32x4*)(&sCM[(wave + i) * 16 + g4]);
#pragma unroll
    for (int r = 0; r < 4; r++) {
      float sv = acc[i][r] + cm[r];
      if (i == 0) {                      // mask if key offset < q offset
        if (g4 + r < cl) sv = -3.0e38f;
      } else if (i == 16) {              // mask if key offset > q offset
        if (g4 + r > cl) sv = -3.0e38f;
      }
      float p = exp2f(sv);               // masked -> exact 0
      acc[i][r] = p;
      lsum += p;
    }
  }
  lsum += __shfl_xor(lsum, 16);
  lsum += __shfl_xor(lsum, 32);  // lanes {cl, cl+16, cl+32, cl+48} share sum

  __syncthreads();  // all waves done reading K -> safe to alias P over it

  // write P (bf16) packed b64: row cl, 4 consecutive keys per tile
  __hip_bfloat16* sp = sKP + wave * 5248;
#pragma unroll
  for (int i = 0; i < 17; i++) {
    ushort4 pk;
    pk.x = f2bf(acc[i][0]); pk.y = f2bf(acc[i][1]);
    pk.z = f2bf(acc[i][2]); pk.w = f2bf(acc[i][3]);
    *(ushort4*)(&sp[cl * 328 + (wave + i) * 16 + g4]) = pk;
  }
  {  // zero the one extra tile the 32-aligned PV k-steps touch
    const int zt = (wave & 1) ? (wave - 1) : (wave + 17);
    ushort4 zz = {0, 0, 0, 0};
    *(ushort4*)(&sp[cl * 328 + zt * 16 + g4]) = zz;
  }
  // no further barrier: each wave reads only its own strip

  // PV: 9 k-steps of 32 keys; V B-frags from VT3, fully dense
  f32x4 oacc[4] = {};
  const int k0 = wave >> 1;  // k-step base: abs keys [k0*32, k0*32+288)
  const __hip_bfloat16* vbase = vt + (size_t)bh * 131072;
#pragma unroll
  for (int ks = 0; ks < 9; ks++) {
    const int kk = (k0 + ks) * 32 + ko;   // abs key col, %8==0
    bf16x8 pa = *(const bf16x8*)(&sp[cl * 328 + kk]);
    int tv = t0 + kk; tv = min(max(tv, 0), 2040);  // tv%8==0
    const __hip_bfloat16* vrow = vbase + (tv >> 3) * 512;
#pragma unroll
    for (int ni = 0; ni < 4; ni++) {
      const int d = ni * 16 + cl;
      bf16x8 vb = *(const bf16x8*)(vrow + d * 8);
      oacc[ni] = __builtin_amdgcn_mfma_f32_16x16x32_bf16(pa, vb, oacc[ni], 0, 0, 0);
    }
  }

  // epilogue: /l (broadcast from lane g4+r), pm-zero, store vals[s][h*64+d]
#pragma unroll
  for (int r = 0; r < 4; r++) {
    const float ls = __shfl(lsum, g4 + r);  // lane g4+r holds row g4+r sum
    float linv = 1.0f / fmaxf(ls, 1e-20f);
    const int qr = wave * 16 + g4 + r;
    if (sCM[qr + 128] != 0.0f) linv = 0.0f;  // fully-masked query -> 0
    const size_t obase = ((size_t)(b * 2048 + s0 + qr)) * 512 + h * 64 + cl;
#pragma unroll
    for (int ni = 0; ni < 4; ni++)
      vals[obase + ni * 16] = __float2bfloat16(oacc[ni][r] * linv);
  }
}

// ---------------- output projection GEMM (64x64 tile, BK=128, swizzled) -----
// Grid 64x8 = 512 blocks -> 2 blocks/CU (LDS 32KB).
__global__ __launch_bounds__(256) void gemm_out(
    const __hip_bfloat16* __restrict__ A, const __hip_bfloat16* __restrict__ Bw,
    const float* __restrict__ bias, float* __restrict__ C) {
  __shared__ __hip_bfloat16 As[64 * 128];  // 16KB
  __shared__ __hip_bfloat16 Bs[64 * 128];

  const int tid = threadIdx.x, wave = tid >> 6, lane = tid & 63;
  const int m0 = blockIdx.x * 64, n0 = blockIdx.y * 64;
  const int wm = (wave >> 1) * 32, wn = (wave & 1) * 32;
  const int cl = lane & 15, ko = (lane >> 4) * 8;
  const int srow = lane >> 4;  // row within 4-row group

  f32x4 acc[2][2] = {};

  for (int k0 = 0; k0 < 512; k0 += 128) {
    __syncthreads();
#pragma unroll
    for (int c = 0; c < 4; c++) {  // A: 64 rows = 16 groups of 4, 4/wave
      const int R = (wave + c * 4) * 4;
      const int scol = 8 * ((lane & 15) ^ ((R & 4) + srow));
      ldsdma16(&As[R * 128], A + (size_t)(m0 + R + srow) * 512 + k0 + scol);
    }
#pragma unroll
    for (int c = 0; c < 4; c++) {  // B: 64 rows = 16 groups of 4, 4/wave
      const int R = (wave + c * 4) * 4;
      const int scol = 8 * ((lane & 15) ^ ((R & 4) + srow));
      ldsdma16(&Bs[R * 128], Bw + (size_t)(n0 + R + srow) * 512 + k0 + scol);
    }
    __syncthreads();

#pragma unroll
    for (int ks = 0; ks < 4; ks++) {
      bf16x8 af[2], bf[2];
#pragma unroll
      for (int i = 0; i < 2; i++) {
        const int row = wm + cl + i * 16;
        af[i] = *(const bf16x8*)(
            &As[row * 128 + ((ks * 32 + ko) ^ ((row & 7) << 3))]);
      }
#pragma unroll
      for (int i = 0; i < 2; i++) {
        const int row = wn + cl + i * 16;
        bf[i] = *(const bf16x8*)(
            &Bs[row * 128 + ((ks * 32 + ko) ^ ((row & 7) << 3))]);
      }
#pragma unroll
      for (int mi = 0; mi < 2; mi++)
#pragma unroll
        for (int ni = 0; ni < 2; ni++)
          acc[mi][ni] = __builtin_amdgcn_mfma_f32_16x16x32_bf16(
              af[mi], bf[ni], acc[mi][ni], 0, 0, 0);
    }
  }

  const int crow = (lane >> 4) * 4;
#pragma unroll
  for (int mi = 0; mi < 2; mi++) {
#pragma unroll
    for (int ni = 0; ni < 2; ni++) {
      const int n = n0 + wn + ni * 16 + cl;
      const float bv = bias[n];
      const int mb = m0 + wm + mi * 16 + crow;
#pragma unroll
      for (int r = 0; r < 4; r++)
        C[(size_t)(mb + r) * 512 + n] = acc[mi][ni][r] + bv;
    }
  }
}

extern "C" void kernel_launch(void* const* d_in, const int* in_sizes, int n_in,
                              void* d_out, int out_size, void* d_ws, size_t ws_size,
                              hipStream_t stream) {
  const float* x     = (const float*)d_in[0];   // (2,2048,512)
  const int*   pm    = (const int*)d_in[1];     // (2,2048)
  const float* qkv_w = (const float*)d_in[2];   // (1536,512)
  const float* qkv_b = (const float*)d_in[3];   // (1536,)
  const float* o_w   = (const float*)d_in[4];   // (512,512)
  const float* o_b   = (const float*)d_in[5];   // (512,)
  float* out = (float*)d_out;                   // (2,2048,512)

  __hip_bfloat16* wsb   = (__hip_bfloat16*)d_ws;
  __hip_bfloat16* xb    = wsb;               // 2097152
  __hip_bfloat16* wqkvb = wsb + 2097152;     // 786432
  __hip_bfloat16* wob   = wsb + 2883584;     // 262144
  __hip_bfloat16* qp    = wsb + 3145728;     // 2097152  [bh][s][64] (scaled)
  __hip_bfloat16* kp    = wsb + 5242880;     // 2097152  [bh][s][64]
  __hip_bfloat16* vt    = wsb + 7340032;     // 2097152  VT3[bh][k/8][d][k%8]
  __hip_bfloat16* vals  = wsb + 9437184;     // 2097152  [s][512]

  dim3 blk(256);
  cvt3_kernel<<<dim3(1024), blk, 0, stream>>>(
      x, (unsigned short*)xb, 2097152,
      qkv_w, (unsigned short*)wqkvb, 786432,
      o_w, (unsigned short*)wob, 262144);
  gemm_qkv<<<dim3(32, 16), blk, 0, stream>>>(
      xb, wqkvb, qkv_b, qp, kp, (unsigned short*)vt);
  attn_mfma<<<dim3(512), blk, 0, stream>>>(qp, kp, vt, pm, vals);
  gemm_out<<<dim3(64, 8), blk, 0, stream>>>(vals, wob, o_b, out);
}